// Round 10
// baseline (258.273 us; speedup 1.0000x reference)
//
#include <hip/hip_runtime.h>

// QuantLinearFP8: out[m,n] = sum_k x[m,k] * w[n,k] * scale[n, k/128] + bias[n]
// M=64, K=4096, N=11008, G=128.
//
// R13: R12 (NT w staging, -10us confirmed) + OCCUPANCY 4 blocks/CU.
// Post-NT the BW plateau is gone -> outstanding-request depth is the lever:
// 3/CU x 4 waves x 6 loads ~ 4.5 KB in flight < ~9 KB needed for 6.3 TB/s
// at ~900cy. Changes vs R12 (one lever: occupancy):
//  - __launch_bounds__(256, 4); LDS = 5 x 8 KB = 40 KB = 160/4 exactly.
//  - x register ring shrunk 4 -> 2 slots (-32 VGPR, ~98 total <= 128 so
//    4 blocks/CU is VGPR-feasible). x prefetch distance 2 (xf is a hot
//    512 KB L2/L3 surface, ~200cy); w keeps distance-4 via the LDS ring.
//  - split-depth vmcnt ledger (verified stage-by-stage):
//    issue order: [start s] W(s+4) ... wait ... compute ... [end s] X(s+2).
//    At stage-s wait point in-flight = 18: W(s..s+4)=10 + X(s),X(s+1)=8.
//    Retain W(s+1..s+4)=8 + X(s+1)=4 -> vmcnt(12) drains exactly W(s)+X(s).
//    Tail: s=12 -> 10, s=13 -> 8, s=14 -> 6, s=15 -> 0.
// Everything else R12 verbatim: wave-private w LDS ring, zero barriers,
// XOR-swizzled source chunks + same XOR on ds_read, NT (aux=2) w staging,
// atomic split-K epilogue into bias-initialized out.
// ws layout: only xf bf16 (512 KB) at offset 0.

#define Md 64
#define Kd 4096
#define Nd 11008
#define NGROUPS 32
#define BN 64
#define KSPLIT 8
#define KCHUNK (Kd / KSPLIT)     // 512
#define NST (KCHUNK / 32)        // 16 BK=32 stages per chunk
#define NBUF 5                   // w LDS ring
#define DISTW 4                  // w prefetch distance (LDS ring)
#define DISTX 2                  // x prefetch distance (reg ring)

typedef __attribute__((ext_vector_type(8))) __bf16 bf16x8;
typedef __attribute__((ext_vector_type(4))) float f32x4;

#define AS1 __attribute__((address_space(1)))
#define AS3 __attribute__((address_space(3)))

// blocks [0,128):   xf[kb][t][lane][j] = x[t*16+(lane&15)][kb*32+(lane>>4)*8+j]
// blocks [128,816): out[i] = bias[i % Nd]  (bias pre-init for atomic split-K)
__global__ __launch_bounds__(256)
void prep(const float* __restrict__ x, __bf16* __restrict__ xf,
          const float* __restrict__ bias, float* __restrict__ out)
{
    if (blockIdx.x < 128) {
        const int tid  = blockIdx.x * 256 + threadIdx.x;  // frag id, 32768
        const int lane = tid & 63;
        const int t    = (tid >> 6) & 3;
        const int kb   = tid >> 8;
        const int row  = t * 16 + (lane & 15);
        const int col  = kb * 32 + (lane >> 4) * 8;
        const float4 a = *(const float4*)(x + (size_t)row * Kd + col);
        const float4 b = *(const float4*)(x + (size_t)row * Kd + col + 4);
        bf16x8 v = {(__bf16)a.x, (__bf16)a.y, (__bf16)a.z, (__bf16)a.w,
                    (__bf16)b.x, (__bf16)b.y, (__bf16)b.z, (__bf16)b.w};
        *(bf16x8*)(xf + (size_t)tid * 8) = v;
    } else {
        const int i4 = (blockIdx.x - 128) * 256 + threadIdx.x; // 176128 = Md*Nd/4
        const int n  = (i4 * 4) % Nd;                          // Nd % 4 == 0
        *(float4*)(out + (size_t)i4 * 4) = *(const float4*)(bias + n);
    }
}

__global__ __launch_bounds__(256, 4)
void qlinear_pass1(const float* __restrict__ w,
                   const __bf16* __restrict__ xf,
                   const float* __restrict__ scale,
                   float* __restrict__ out)
{
    const int tid  = threadIdx.x;
    const int wv   = tid >> 6;         // wave -> n-substripe
    const int lane = tid & 63;
    const int quad = lane >> 4;
    const int ln   = lane & 15;

    const int n0 = blockIdx.x * BN;
    const int ky = blockIdx.y;
    const int k0 = ky * KCHUNK;

    __shared__ alignas(16) float lds_w[NBUF][BN * 32];   // 5 x 8 KB = 40 KB

    // wave-private w staging: 2 issues/stage cover rows wv*16..+15
    // (8 rows x 128 B contiguous each). Source 16B-chunk XOR-swizzled by row
    // so linear LDS holds the swizzled layout (rule 21).
    const float* src[2];
    #pragma unroll
    for (int j = 0; j < 2; ++j) {
        const int r   = wv * 16 + j * 8 + (lane >> 3);   // row this lane feeds
        const int c16 = (lane & 7) ^ (r & 7);            // swizzled chunk 0..7
        src[j] = w + (size_t)(n0 + r) * Kd + k0 + c16 * 4;
    }

// aux=2 -> CPol NT: w single-use; don't allocate in (dirty) L3 -> no
// writeback storm from the harness's 688 MB poison fill (R12: -10 us).
#define WSTAGE(S, B)                                                           \
    do {                                                                       \
        _Pragma("unroll")                                                      \
        for (int j = 0; j < 2; ++j)                                           \
            __builtin_amdgcn_global_load_lds(                                  \
                (const AS1 void*)(src[j] + (S) * 32),                          \
                (AS3 void*)&lds_w[B][(wv * 16 + j * 8) * 32], 16, 0, 2);       \
    } while (0)

    // x register ring: 4 frags per stage, 2 slots, prefetch distance 2
    const __bf16* xp = xf + (size_t)ky * NST * 4 * 512 + (size_t)lane * 8;
    bf16x8 xr[2][4];

#define XLOAD(SLOT, S)                                                         \
    do {                                                                       \
        _Pragma("unroll")                                                      \
        for (int t = 0; t < 4; ++t)                                           \
            xr[SLOT][t] = *(const bf16x8*)(xp + ((size_t)(S) * 4 + t) * 512);  \
    } while (0)

    // scales: load and fully drain BEFORE the counted window starts
    const int nrow = n0 + wv * 16 + ln;
    float4 sc4 = *(const float4*)(scale + (size_t)nrow * NGROUPS + ky * 4);
    asm volatile("s_waitcnt vmcnt(0)" ::: "memory");
    const float sc[4] = {sc4.x, sc4.y, sc4.z, sc4.w};

    // frag-read row + swizzle key
    const int rr = wv * 16 + ln;
    const int rx = rr & 7;

    f32x4 acc[4], pg[4];
    #pragma unroll
    for (int t = 0; t < 4; ++t) {
        acc[t] = (f32x4){0.f, 0.f, 0.f, 0.f};
        pg[t]  = (f32x4){0.f, 0.f, 0.f, 0.f};
    }

    // prologue: W 4 ahead, X 2 ahead (interleaved oldest-first)
    WSTAGE(0, 0); XLOAD(0, 0);
    WSTAGE(1, 1); XLOAD(1, 1);
    WSTAGE(2, 2);
    WSTAGE(3, 3);

    #pragma unroll
    for (int s = 0; s < NST; ++s) {
        // issue next w stage (top of window)
        if (s + DISTW < NST) WSTAGE(s + DISTW, (s + DISTW) % NBUF);

        // counted wait: drain exactly W(s)+X(s), retain the newer window.
        if (s + DISTW < NST)     asm volatile("s_waitcnt vmcnt(12)" ::: "memory");
        else if (s == NST - 4)   asm volatile("s_waitcnt vmcnt(10)" ::: "memory");
        else if (s == NST - 3)   asm volatile("s_waitcnt vmcnt(8)"  ::: "memory");
        else if (s == NST - 2)   asm volatile("s_waitcnt vmcnt(6)"  ::: "memory");
        else                     asm volatile("s_waitcnt vmcnt(0)"  ::: "memory");
        __builtin_amdgcn_sched_barrier(0);

        // w frag: two swizzled 16B chunks of (wave-private) row rr
        const int buf = s % NBUF;
        const int cA  = (quad * 2) ^ rx;
        const int cB  = (quad * 2 + 1) ^ rx;
        f32x4 fa = *(const f32x4*)&lds_w[buf][rr * 32 + cA * 4];
        f32x4 fb = *(const f32x4*)&lds_w[buf][rr * 32 + cB * 4];
        bf16x8 wf = {(__bf16)fa.x, (__bf16)fa.y, (__bf16)fa.z, (__bf16)fa.w,
                     (__bf16)fb.x, (__bf16)fb.y, (__bf16)fb.z, (__bf16)fb.w};

        #pragma unroll
        for (int t = 0; t < 4; ++t)
            pg[t] = __builtin_amdgcn_mfma_f32_16x16x32_bf16(xr[s & 1][t], wf,
                                                            pg[t], 0, 0, 0);

        // refill the x ring slot just consumed (distance 2)
        if (s + DISTX < NST) XLOAD(s & 1, s + DISTX);

        // per-128k scale group boundary: fold pg into acc
        if ((s & 3) == 3) {
            const float sg = sc[s >> 2];
            #pragma unroll
            for (int t = 0; t < 4; ++t) {
                #pragma unroll
                for (int r = 0; r < 4; ++r) {
                    acc[t][r] += sg * pg[t][r];
                    pg[t][r] = 0.f;
                }
            }
        }
    }

    // atomic split-K epilogue -> out[m][n]  (C/D: m = t*16+quad*4+r, col = ln)
    float* op = out + n0 + wv * 16 + ln;
    #pragma unroll
    for (int t = 0; t < 4; ++t)
        #pragma unroll
        for (int r = 0; r < 4; ++r)
            unsafeAtomicAdd(&op[(size_t)(t * 16 + quad * 4 + r) * Nd], acc[t][r]);
#undef WSTAGE
#undef XLOAD
}

extern "C" void kernel_launch(void* const* d_in, const int* in_sizes, int n_in,
                              void* d_out, int out_size, void* d_ws, size_t ws_size,
                              hipStream_t stream) {
    const float* x     = (const float*)d_in[0];  // [64][4096]
    const float* w     = (const float*)d_in[1];  // [11008][4096]
    const float* scale = (const float*)d_in[2];  // [11008][32]
    const float* bias  = (const float*)d_in[3];  // [11008]
    float* out = (float*)d_out;                  // [64][11008] f32
    float* ws  = (float*)d_ws;                   // xf bf16 (512 KB)

    __bf16* xf = (__bf16*)ws;                    // 16B-aligned

    prep<<<816, 256, 0, stream>>>(x, xf, bias, out);

    dim3 grid1(Nd / BN, KSPLIT);
    qlinear_pass1<<<grid1, 256, 0, stream>>>(w, xf, scale, out);
}